// Round 8
// baseline (1392.952 us; speedup 1.0000x reference)
//
#include <hip/hip_runtime.h>
#include <hip/hip_fp16.h>

typedef unsigned short ushort_t;
typedef short bf16x8 __attribute__((ext_vector_type(8)));
typedef float f32x4 __attribute__((ext_vector_type(4)));
typedef _Float16 f16x8 __attribute__((ext_vector_type(8)));

#define B_SZ 32
#define T_SZ 256
#define V_SZ 10000
#define E_DIM 300
#define M_DIM 128
#define H_SZ 256

__device__ __forceinline__ ushort_t f2bf(float f) {
  unsigned u = __float_as_uint(f);
  unsigned r = u + 0x7fffu + ((u >> 16) & 1u);
  return (ushort_t)(r >> 16);
}

// ---------------- elementwise cast f32 -> bf16 ----------------
__global__ void k_cast_bf16(const float* __restrict__ in, ushort_t* __restrict__ out, int n) {
  int i = blockIdx.x * blockDim.x + threadIdx.x;
  if (i < n) out[i] = f2bf(in[i]);
}

// ---------------- transpose + cast: out[c][r] = in[r][c], zero-padded ----------------
// MODE 0: bf16 output, MODE 1: f16 output. out dims [Cp][Rp].
template <int MODE>
__global__ void k_transpose_cast(const float* __restrict__ in, ushort_t* __restrict__ out,
                                 int R, int C, int Rp, int Cp) {
  __shared__ float tile[32][33];
  int c0 = blockIdx.x * 32, r0 = blockIdx.y * 32;
  int tx = threadIdx.x, ty = threadIdx.y;  // (32,8)
#pragma unroll
  for (int i = 0; i < 32; i += 8) {
    int r = r0 + ty + i, c = c0 + tx;
    tile[ty + i][tx] = (r < R && c < C) ? in[(size_t)r * C + c] : 0.f;
  }
  __syncthreads();
#pragma unroll
  for (int i = 0; i < 32; i += 8) {
    int c = c0 + ty + i, r = r0 + tx;
    if (c < Cp && r < Rp) {
      float v = tile[tx][ty + i];
      if (MODE == 0) {
        out[(size_t)c * Rp + r] = f2bf(v);
      } else {
        __half h = __float2half(v);
        out[(size_t)c * Rp + r] = *(ushort_t*)&h;
      }
    }
  }
}

// ---------------- fuse: x_b[m][kp] = bf16(xtmp[m][kp] + E[words[m]][kp]) (kp<300), else 0 ----
__global__ void k_xfuse(const float* __restrict__ xtmp, const float* __restrict__ E,
                        const int* __restrict__ words, ushort_t* __restrict__ xb) {
  int m = blockIdx.x;
  int kp = threadIdx.x;  // 320 threads
  int w = words[m];
  float v = 0.f;
  if (kp < E_DIM) v = xtmp[(size_t)m * 320 + kp] + E[(size_t)w * E_DIM + kp];
  xb[(size_t)m * 320 + kp] = f2bf(v);
}

// ---------------- bf16 MFMA GEMM: C[m][n] = sum_k A[m][k]*BT[n][k] + bias[n] ----------------
// A: [M][K] bf16 row-major. BT: [Npad][K] bf16 row-major (pre-transposed B).
// 128x128 tile per block, 4 waves (2x2 of 64x64), BK=64, XOR-swizzled LDS.
__global__ __launch_bounds__(256, 2) void k_gemm_bt(
    const ushort_t* __restrict__ A, const ushort_t* __restrict__ BT,
    const float* __restrict__ bias, float* __restrict__ C,
    int M, int K, int Nreal, int ldc) {
  __shared__ __align__(16) char smem[32768];
  char* As = smem;            // [128 rows][8 slots of 16B], slot = c16 ^ (row&7)
  char* Bs = smem + 16384;
  const int tid = threadIdx.x;
  const int lane = tid & 63;
  const int w = tid >> 6;
  const int wr = w >> 1, wc = w & 1;
  const int m0 = blockIdx.x * 128;   // m-tile fastest-varying: same-B-panel blocks adjacent
  const int n0 = blockIdx.y * 128;

  f32x4 acc[4][4];
#pragma unroll
  for (int i = 0; i < 4; ++i)
#pragma unroll
    for (int j = 0; j < 4; ++j) acc[i][j] = (f32x4){0.f, 0.f, 0.f, 0.f};

  const int srow = tid >> 3;   // 0..31
  const int sc16 = tid & 7;    // 0..7

  for (int k0 = 0; k0 < K; k0 += 64) {
    __syncthreads();
#pragma unroll
    for (int it = 0; it < 4; ++it) {
      int row = srow + it * 32;
      int slot = sc16 ^ (row & 7);
      bf16x8 va = *(const bf16x8*)(A + (size_t)(m0 + row) * K + k0 + sc16 * 8);
      *(bf16x8*)(As + row * 128 + (slot << 4)) = va;
      bf16x8 vb = *(const bf16x8*)(BT + (size_t)(n0 + row) * K + k0 + sc16 * 8);
      *(bf16x8*)(Bs + row * 128 + (slot << 4)) = vb;
    }
    __syncthreads();

    bf16x8 af[4][2], bfr[4][2];
#pragma unroll
    for (int mi = 0; mi < 4; ++mi) {
      int r = wr * 64 + mi * 16 + (lane & 15);
#pragma unroll
      for (int kk = 0; kk < 2; ++kk) {
        int c16 = kk * 4 + (lane >> 4);
        af[mi][kk] = *(const bf16x8*)(As + r * 128 + ((c16 ^ (r & 7)) << 4));
      }
    }
#pragma unroll
    for (int ni = 0; ni < 4; ++ni) {
      int r = wc * 64 + ni * 16 + (lane & 15);
#pragma unroll
      for (int kk = 0; kk < 2; ++kk) {
        int c16 = kk * 4 + (lane >> 4);
        bfr[ni][kk] = *(const bf16x8*)(Bs + r * 128 + ((c16 ^ (r & 7)) << 4));
      }
    }
#pragma unroll
    for (int mi = 0; mi < 4; ++mi)
#pragma unroll
      for (int ni = 0; ni < 4; ++ni)
#pragma unroll
        for (int kk = 0; kk < 2; ++kk)
          acc[mi][ni] = __builtin_amdgcn_mfma_f32_16x16x32_bf16(af[mi][kk], bfr[ni][kk],
                                                                acc[mi][ni], 0, 0, 0);
  }

  // epilogue: D row=(lane>>4)*4+reg, col=lane&15  [verified m89 layout]
  const int rbase = m0 + wr * 64 + (lane >> 4) * 4;
  const int cbase = n0 + wc * 64 + (lane & 15);
#pragma unroll
  for (int ni = 0; ni < 4; ++ni) {
    int n = cbase + ni * 16;
    if (n < Nreal) {
      float bn = bias[n];
#pragma unroll
      for (int mi = 0; mi < 4; ++mi) {
#pragma unroll
        for (int rg = 0; rg < 4; ++rg) {
          int mrow = rbase + mi * 16 + rg;
          C[(size_t)mrow * ldc + n] = acc[mi][ni][rg] + bn;
        }
      }
    }
  }
}

// ---------------- GRU: 2-batch antiphase MFMA pipeline, 16 blocks ----------------
// 512 threads = 8 waves, 2 waves/SIMD. Wave w owns U cols [w*96,w*96+96) as ONE shared
// Ufrag[6][8] (f16, 192 regs, AGPR-resident — round-2-proven no-spill at VGPR_Count=128).
// Each block advances TWO independent batches (bA, bB) in antiphase: while batch A's
// 48 MFMAs/wave fill the matrix pipe (~930 cyc/SIMD), batch B's gates/h-update/seqb
// store/gx prefetch issue in its shadow — and vice versa. bu folded into acc init.
// seqb stores deferred to the opposite phase start so the barrier's vmcnt drain hides
// under MFMA. Per iteration = 1 timestep for BOTH batches.
__global__ __launch_bounds__(512, 2) void k_gru(
    const float* __restrict__ gx, const ushort_t* __restrict__ UT,
    const float* __restrict__ bu, const int* __restrict__ words,
    ushort_t* __restrict__ seqb) {
  const int bA = blockIdx.x * 2;
  const int bB = bA + 1;
  const int tid = threadIdx.x;
  const int lane = tid & 63;
  const int w = tid >> 6;  // 0..7

  __shared__ __align__(16) _Float16 hA[16 * 256];  // rows 1..15 stay zero
  __shared__ __align__(16) _Float16 hB[16 * 256];
  __shared__ float ghA[768];
  __shared__ float ghB[768];
  __shared__ int wA_s[T_SZ];
  __shared__ int wB_s[T_SZ];

  for (int i = tid; i < 16 * 256; i += 512) {
    hA[i] = (_Float16)0.f;
    hB[i] = (_Float16)0.f;
  }
  if (tid < T_SZ) {
    wA_s[tid] = words[bA * T_SZ + tid];
    wB_s[tid] = words[bB * T_SZ + tid];
  }

  // B-fragments (shared by both batches): Ufrag[ni][kk] elem j =
  //   UT[n0 + ni*16 + (lane&15)][kk*32 + (lane>>4)*8 + j]   (UT: [768][256] f16)
  f16x8 Ufrag[6][8];
  const int n0 = w * 96;
  {
    const ushort_t* src = UT + (size_t)(n0 + (lane & 15)) * 256 + (lane >> 4) * 8;
#pragma unroll
    for (int ni = 0; ni < 6; ++ni) {
#pragma unroll
      for (int kk = 0; kk < 8; ++kk)
        Ufrag[ni][kk] = *(const f16x8*)(src + (size_t)ni * 16 * 256 + kk * 32);
    }
  }
  float bub[6];
#pragma unroll
  for (int ni = 0; ni < 6; ++ni) bub[ni] = (lane < 16) ? bu[n0 + ni * 16 + lane] : 0.f;

  __syncthreads();

  const float* gxA = gx + (size_t)bA * T_SZ * 768;
  const float* gxB = gx + (size_t)bB * T_SZ * 768;
  // gA* holds gxA[t] for gates_A(t) in phase 2; gB* holds gxB[t-1] for gates_B(t-1) in phase 1.
  float gAz = 0.f, gAr = 0.f, gAn = 0.f, gBz = 0.f, gBr = 0.f, gBn = 0.f;
  if (tid < H_SZ) {
    gAz = gxA[tid];
    gAr = gxA[H_SZ + tid];
    gAn = gxA[2 * H_SZ + tid];
  }
  float hOldA = 0.f, hOldB = 0.f, pendA = 0.f, pendB = 0.f;

  // A-frag LDS address: row=(lane&15), chunk c = kk*4 + (lane>>4), swizzle c ^= (row&7).
  const int arow = lane & 15;
  const int abase = arow * 512;  // bytes (256 f16 per row)
  const int asub = lane >> 4;
  const int aswz = arow & 7;

  for (int t = 0; t < T_SZ; ++t) {
    // ================= phase 1: MFMA(A) || gates_B(t-1) =================
    if (t > 0 && tid < H_SZ)
      seqb[((size_t)bA * T_SZ + (t - 1)) * H_SZ + tid] = f2bf(pendA);  // drains under MFMA

    // prefetch gxA[t+1] (for next iter's phase 2) and gxB[t] (for next iter's phase 1)
    float gAz_n = 0.f, gAr_n = 0.f, gAn_n = 0.f, gBz_n = 0.f, gBr_n = 0.f, gBn_n = 0.f;
    if (tid < H_SZ) {
      if (t + 1 < T_SZ) {
        const float* g1 = gxA + (size_t)(t + 1) * 768;
        gAz_n = g1[tid];
        gAr_n = g1[H_SZ + tid];
        gAn_n = g1[2 * H_SZ + tid];
      }
      const float* g2 = gxB + (size_t)t * 768;
      gBz_n = g2[tid];
      gBr_n = g2[H_SZ + tid];
      gBn_n = g2[2 * H_SZ + tid];
    }

    f32x4 acc[6];
#pragma unroll
    for (int ni = 0; ni < 6; ++ni) acc[ni] = (f32x4){bub[ni], 0.f, 0.f, 0.f};
#pragma unroll
    for (int kk = 0; kk < 8; ++kk) {
      int c = kk * 4 + asub;
      f16x8 afrag = *(const f16x8*)((const char*)hA + abase + ((c ^ aswz) << 4));
#pragma unroll
      for (int ni = 0; ni < 6; ++ni)
        acc[ni] = __builtin_amdgcn_mfma_f32_16x16x32_f16(afrag, Ufrag[ni][kk], acc[ni], 0, 0, 0);
    }

    if (t > 0 && tid < H_SZ) {  // gates for batch B, step t-1 (in MFMA-A's shadow)
      float hz = ghB[tid];
      float hr = ghB[H_SZ + tid];
      float hn = ghB[2 * H_SZ + tid];
      float z = 1.f / (1.f + __expf(-(gBz + hz)));
      float r = 1.f / (1.f + __expf(-(gBr + hr)));
      float nv = 2.f / (1.f + __expf(-2.f * (gBn + r * hn))) - 1.f;
      float hnew = (wB_s[t - 1] != 0) ? (z * hOldB + (1.f - z) * nv) : hOldB;
      hOldB = hnew;
      pendB = hnew;
      hB[tid] = (_Float16)hnew;  // row 0 (swizzle identity for row 0)
    }
    // C row 0 = lanes 0..15, reg 0  [m89 layout]
    if (lane < 16) {
#pragma unroll
      for (int ni = 0; ni < 6; ++ni) ghA[n0 + ni * 16 + lane] = acc[ni][0];
    }
    __syncthreads();

    // ================= phase 2: MFMA(B) || gates_A(t) =================
    if (t > 0 && tid < H_SZ)
      seqb[((size_t)bB * T_SZ + (t - 1)) * H_SZ + tid] = f2bf(pendB);

    f32x4 acc2[6];
#pragma unroll
    for (int ni = 0; ni < 6; ++ni) acc2[ni] = (f32x4){bub[ni], 0.f, 0.f, 0.f};
#pragma unroll
    for (int kk = 0; kk < 8; ++kk) {
      int c = kk * 4 + asub;
      f16x8 afrag = *(const f16x8*)((const char*)hB + abase + ((c ^ aswz) << 4));
#pragma unroll
      for (int ni = 0; ni < 6; ++ni)
        acc2[ni] = __builtin_amdgcn_mfma_f32_16x16x32_f16(afrag, Ufrag[ni][kk], acc2[ni], 0, 0, 0);
    }

    if (tid < H_SZ) {  // gates for batch A, step t (in MFMA-B's shadow)
      float hz = ghA[tid];
      float hr = ghA[H_SZ + tid];
      float hn = ghA[2 * H_SZ + tid];
      float z = 1.f / (1.f + __expf(-(gAz + hz)));
      float r = 1.f / (1.f + __expf(-(gAr + hr)));
      float nv = 2.f / (1.f + __expf(-2.f * (gAn + r * hn))) - 1.f;
      float hnew = (wA_s[t] != 0) ? (z * hOldA + (1.f - z) * nv) : hOldA;
      hOldA = hnew;
      pendA = hnew;
      hA[tid] = (_Float16)hnew;
    }
    if (lane < 16) {
#pragma unroll
      for (int ni = 0; ni < 6; ++ni) ghB[n0 + ni * 16 + lane] = acc2[ni][0];
    }
    __syncthreads();

    gAz = gAz_n;
    gAr = gAr_n;
    gAn = gAn_n;
    gBz = gBz_n;
    gBr = gBr_n;
    gBn = gBn_n;
  }

  // epilogue: final A store + gates_B(T-1) + its store
  if (tid < H_SZ) {
    seqb[((size_t)bA * T_SZ + (T_SZ - 1)) * H_SZ + tid] = f2bf(pendA);
    float hz = ghB[tid];
    float hr = ghB[H_SZ + tid];
    float hn = ghB[2 * H_SZ + tid];
    float z = 1.f / (1.f + __expf(-(gBz + hz)));
    float r = 1.f / (1.f + __expf(-(gBr + hr)));
    float nv = 2.f / (1.f + __expf(-2.f * (gBn + r * hn))) - 1.f;
    float hnew = (wB_s[T_SZ - 1] != 0) ? (z * hOldB + (1.f - z) * nv) : hOldB;
    seqb[((size_t)bB * T_SZ + (T_SZ - 1)) * H_SZ + tid] = f2bf(hnew);
  }
}

// ---------------- launcher ----------------
extern "C" void kernel_launch(void* const* d_in, const int* in_sizes, int n_in,
                              void* d_out, int out_size, void* d_ws, size_t ws_size,
                              hipStream_t stream) {
  const int*   words = (const int*)d_in[0];    // [32,256]
  const float* midis = (const float*)d_in[1];  // [32,256,128]
  const float* E     = (const float*)d_in[2];  // [10000,300]
  const float* Wm    = (const float*)d_in[3];  // [128,300]
  const float* bm    = (const float*)d_in[4];  // [300]
  const float* Wx    = (const float*)d_in[5];  // [300,768]
  const float* bx    = (const float*)d_in[6];  // [768]
  const float* U     = (const float*)d_in[7];  // [256,768]
  const float* bu    = (const float*)d_in[8];  // [768]
  const float* Wo    = (const float*)d_in[9];  // [256,10000]
  const float* bo    = (const float*)d_in[10]; // [10000]
  float* out = (float*)d_out;

  const int MT = B_SZ * T_SZ;  // 8192
  size_t off = 0;
  auto alloc = [&](size_t bytes) -> void* {
    void* p = (char*)d_ws + off;
    off += (bytes + 255) & ~(size_t)255;
    return p;
  };
  ushort_t* mid_b = (ushort_t*)alloc((size_t)MT * 128 * 2);
  ushort_t* WmT   = (ushort_t*)alloc((size_t)384 * 128 * 2);
  float*    xtmp  = (float*)   alloc((size_t)MT * 320 * 4);
  ushort_t* x_b   = (ushort_t*)alloc((size_t)MT * 320 * 2);
  ushort_t* WxT   = (ushort_t*)alloc((size_t)768 * 320 * 2);
  float*    gx    = (float*)   alloc((size_t)MT * 768 * 4);
  ushort_t* UT    = (ushort_t*)alloc((size_t)768 * 256 * 2);
  ushort_t* seq_b = (ushort_t*)alloc((size_t)MT * 256 * 2);
  ushort_t* WoT   = (ushort_t*)alloc((size_t)10112 * 256 * 2);
  (void)ws_size;

  // prep: casts + transposes
  k_cast_bf16<<<(MT * 128 + 255) / 256, 256, 0, stream>>>(midis, mid_b, MT * 128);
  k_transpose_cast<0><<<dim3(12, 4),  dim3(32, 8), 0, stream>>>(Wm, WmT, 128, 300, 128, 384);
  k_transpose_cast<0><<<dim3(24, 10), dim3(32, 8), 0, stream>>>(Wx, WxT, 300, 768, 320, 768);
  k_transpose_cast<0><<<dim3(316, 8), dim3(32, 8), 0, stream>>>(Wo, WoT, 256, 10000, 256, 10112);
  k_transpose_cast<1><<<dim3(24, 8),  dim3(32, 8), 0, stream>>>(U, UT, 256, 768, 256, 768);

  // xtmp = midis @ Wm + bm   (M=8192, K=128, Npad=384, Nreal=300, ldc=320)
  k_gemm_bt<<<dim3(64, 3), 256, 0, stream>>>(mid_b, WmT, bm, xtmp, MT, 128, 300, 320);
  // x_b = bf16(xtmp + E[words]) with k-pad zeros
  k_xfuse<<<MT, 320, 0, stream>>>(xtmp, E, words, x_b);
  // gx = x @ Wx + bx   (K=320, N=768)
  k_gemm_bt<<<dim3(64, 6), 256, 0, stream>>>(x_b, WxT, bx, gx, MT, 320, 768, 768);
  // GRU -> seq_b (bf16), 2-batch antiphase MFMA pipeline
  k_gru<<<B_SZ / 2, 512, 0, stream>>>(gx, UT, bu, words, seq_b);
  // logits = seq @ Wo + bo   (K=256, Npad=10112, Nreal=10000)
  k_gemm_bt<<<dim3(64, 79), 256, 0, stream>>>(seq_b, WoT, bo, out, MT, 256, 10000, 10000);
}

// Round 9
// 471.223 us; speedup vs baseline: 2.9560x; 2.9560x over previous
//
#include <hip/hip_runtime.h>
#include <hip/hip_fp16.h>

typedef unsigned short ushort_t;
typedef short bf16x8 __attribute__((ext_vector_type(8)));
typedef float f32x4 __attribute__((ext_vector_type(4)));
typedef _Float16 f16x8 __attribute__((ext_vector_type(8)));

#define B_SZ 32
#define T_SZ 256
#define V_SZ 10000
#define E_DIM 300
#define M_DIM 128
#define H_SZ 256

__device__ __forceinline__ ushort_t f2bf(float f) {
  unsigned u = __float_as_uint(f);
  unsigned r = u + 0x7fffu + ((u >> 16) & 1u);
  return (ushort_t)(r >> 16);
}

// async global->LDS, 16B per lane: per-lane GLOBAL src, wave-uniform LDS base (+lane*16 by HW)
__device__ __forceinline__ void stage16(const void* g, void* l) {
  __builtin_amdgcn_global_load_lds((const __attribute__((address_space(1))) void*)g,
                                   (__attribute__((address_space(3))) void*)l, 16, 0, 0);
}

// ---------------- elementwise cast f32 -> bf16 ----------------
__global__ void k_cast_bf16(const float* __restrict__ in, ushort_t* __restrict__ out, int n) {
  int i = blockIdx.x * blockDim.x + threadIdx.x;
  if (i < n) out[i] = f2bf(in[i]);
}

// ---------------- transpose + cast: out[c][r] = in[r][c], zero-padded ----------------
// MODE 0: bf16 output, MODE 1: f16 output. out dims [Cp][Rp].
template <int MODE>
__global__ void k_transpose_cast(const float* __restrict__ in, ushort_t* __restrict__ out,
                                 int R, int C, int Rp, int Cp) {
  __shared__ float tile[32][33];
  int c0 = blockIdx.x * 32, r0 = blockIdx.y * 32;
  int tx = threadIdx.x, ty = threadIdx.y;  // (32,8)
#pragma unroll
  for (int i = 0; i < 32; i += 8) {
    int r = r0 + ty + i, c = c0 + tx;
    tile[ty + i][tx] = (r < R && c < C) ? in[(size_t)r * C + c] : 0.f;
  }
  __syncthreads();
#pragma unroll
  for (int i = 0; i < 32; i += 8) {
    int c = c0 + ty + i, r = r0 + tx;
    if (c < Cp && r < Rp) {
      float v = tile[tx][ty + i];
      if (MODE == 0) {
        out[(size_t)c * Rp + r] = f2bf(v);
      } else {
        __half h = __float2half(v);
        out[(size_t)c * Rp + r] = *(ushort_t*)&h;
      }
    }
  }
}

// ---------------- fuse: x_b[m][kp] = bf16(xtmp[m][kp] + E[words[m]][kp]) (kp<300), else 0 ----
__global__ void k_xfuse(const float* __restrict__ xtmp, const float* __restrict__ E,
                        const int* __restrict__ words, ushort_t* __restrict__ xb) {
  int m = blockIdx.x;
  int kp = threadIdx.x;  // 320 threads
  int w = words[m];
  float v = 0.f;
  if (kp < E_DIM) v = xtmp[(size_t)m * 320 + kp] + E[(size_t)w * E_DIM + kp];
  xb[(size_t)m * 320 + kp] = f2bf(v);
}

// ---------------- bf16 MFMA GEMM: C[m][n] = sum_k A[m][k]*BT[n][k] + bias[n] ----------------
// A: [M][K] bf16 row-major. BT: [Npad][K] bf16 row-major (pre-transposed B).
// 128x128 tile per block, 4 waves (2x2 of 64x64), BK=64.
// m97 structure: LINEAR LDS [128 rows][64 k] staged via global_load_lds width=16
// (each wave stages 256 disjoint 16B chunks; per-lane global src, uniform LDS base).
// 2 barriers per K-step; swizzle omitted (T2 null in 2-phase 128^2 regime).
__global__ __launch_bounds__(256, 2) void k_gemm_bt(
    const ushort_t* __restrict__ A, const ushort_t* __restrict__ BT,
    const float* __restrict__ bias, float* __restrict__ C,
    int M, int K, int Nreal, int ldc) {
  __shared__ __align__(16) ushort_t As[128 * 64];  // 16KB
  __shared__ __align__(16) ushort_t Bs[128 * 64];  // 16KB
  const int tid = threadIdx.x;
  const int lane = tid & 63;
  const int w = tid >> 6;
  const int wr = w >> 1, wc = w & 1;
  const int m0 = blockIdx.x * 128;   // m-tile fastest-varying: same-B-panel blocks adjacent
  const int n0 = blockIdx.y * 128;

  f32x4 acc[4][4];
#pragma unroll
  for (int i = 0; i < 4; ++i)
#pragma unroll
    for (int j = 0; j < 4; ++j) acc[i][j] = (f32x4){0.f, 0.f, 0.f, 0.f};

  // staging: chunk = it*256 + w*64 + lane; row = chunk>>3, c = chunk&7 (8 chunks/row)
  const int chunk_l = w * 64 + lane;

  for (int k0 = 0; k0 < K; k0 += 64) {
    __syncthreads();  // previous step's ds_reads complete before overwrite
#pragma unroll
    for (int it = 0; it < 4; ++it) {
      const int chunk = it * 256 + chunk_l;
      const int row = chunk >> 3, c = chunk & 7;
      const int base = it * 256 + w * 64;  // wave-uniform chunk base
      stage16(A + (size_t)(m0 + row) * K + k0 + c * 8, (void*)(As + base * 8));
      stage16(BT + (size_t)(n0 + row) * K + k0 + c * 8, (void*)(Bs + base * 8));
    }
    __syncthreads();  // compiler drains vmcnt(0) here -> staging visible

    bf16x8 af[4][2], bfr[4][2];
#pragma unroll
    for (int mi = 0; mi < 4; ++mi) {
      int r = wr * 64 + mi * 16 + (lane & 15);
#pragma unroll
      for (int kk = 0; kk < 2; ++kk) {
        int c16 = kk * 4 + (lane >> 4);
        af[mi][kk] = *(const bf16x8*)(As + r * 64 + c16 * 8);
      }
    }
#pragma unroll
    for (int ni = 0; ni < 4; ++ni) {
      int r = wc * 64 + ni * 16 + (lane & 15);
#pragma unroll
      for (int kk = 0; kk < 2; ++kk) {
        int c16 = kk * 4 + (lane >> 4);
        bfr[ni][kk] = *(const bf16x8*)(Bs + r * 64 + c16 * 8);
      }
    }
#pragma unroll
    for (int mi = 0; mi < 4; ++mi)
#pragma unroll
      for (int ni = 0; ni < 4; ++ni)
#pragma unroll
        for (int kk = 0; kk < 2; ++kk)
          acc[mi][ni] = __builtin_amdgcn_mfma_f32_16x16x32_bf16(af[mi][kk], bfr[ni][kk],
                                                                acc[mi][ni], 0, 0, 0);
  }

  // epilogue: D row=(lane>>4)*4+reg, col=lane&15  [verified m89 layout]
  const int rbase = m0 + wr * 64 + (lane >> 4) * 4;
  const int cbase = n0 + wc * 64 + (lane & 15);
#pragma unroll
  for (int ni = 0; ni < 4; ++ni) {
    int n = cbase + ni * 16;
    if (n < Nreal) {
      float bn = bias[n];
#pragma unroll
      for (int mi = 0; mi < 4; ++mi) {
#pragma unroll
        for (int rg = 0; rg < 4; ++rg) {
          int mrow = rbase + mi * 16 + rg;
          C[(size_t)mrow * ldc + n] = acc[mi][ni][rg] + bn;
        }
      }
    }
  }
}

// ---------------- GRU: MFMA matvec, one block per batch (round-2 proven, 297us) ----------------
// 512 threads = 8 waves. Wave w owns U columns [w*96, w*96+96) as register-resident
// B-fragments (f16, 192 regs, AGPR-resident -> no spill at VGPR_Count=128).
// Per step: h (f16, zero-padded to 16 rows in LDS, XOR-swizzled) read as 8 A-fragments
// per wave, 48 mfma_f32_16x16x32_f16 per wave, gh row 0 scattered to LDS, then
// thread j (0..255) computes gates for output j. 2 barriers/step.
__global__ __launch_bounds__(512, 2) void k_gru(
    const float* __restrict__ gx, const ushort_t* __restrict__ UT,
    const float* __restrict__ bu, const int* __restrict__ words,
    ushort_t* __restrict__ seqb) {
  const int b = blockIdx.x;
  const int tid = threadIdx.x;
  const int lane = tid & 63;
  const int w = tid >> 6;  // 0..7

  __shared__ __align__(16) _Float16 hlds[16 * 256];  // rows 1..15 stay zero
  __shared__ float ghbuf[768];
  __shared__ int words_s[T_SZ];

  for (int i = tid; i < 16 * 256; i += 512) hlds[i] = (_Float16)0.f;
  if (tid < T_SZ) words_s[tid] = words[b * T_SZ + tid];

  // B-fragments: Ufrag[ni][kk] elem j = UT[n0 + ni*16 + (lane&15)][kk*32 + (lane>>4)*8 + j]
  f16x8 Ufrag[6][8];
  {
    const int n0 = w * 96;
    const ushort_t* src = UT + (size_t)(n0 + (lane & 15)) * 256 + (lane >> 4) * 8;
#pragma unroll
    for (int ni = 0; ni < 6; ++ni) {
#pragma unroll
      for (int kk = 0; kk < 8; ++kk)
        Ufrag[ni][kk] = *(const f16x8*)(src + (size_t)ni * 16 * 256 + kk * 32);
    }
  }
  float buz = 0.f, bur = 0.f, bun = 0.f;
  if (tid < H_SZ) {
    buz = bu[tid];
    bur = bu[H_SZ + tid];
    bun = bu[2 * H_SZ + tid];
  }
  __syncthreads();

  const float* gxp = gx + (size_t)b * T_SZ * 768;
  float gxz = 0.f, gxr = 0.f, gxn = 0.f;
  if (tid < H_SZ) {
    gxz = gxp[tid];
    gxr = gxp[H_SZ + tid];
    gxn = gxp[2 * H_SZ + tid];
  }
  float h_old = 0.f;

  // A-frag LDS address: row=(lane&15), chunk c = kk*4 + (lane>>4), swizzle c ^= (row&7).
  const int arow = lane & 15;
  const int abase = arow * 512;  // bytes (256 f16 per row)
  const int asub = lane >> 4;
  const int aswz = arow & 7;

  for (int t = 0; t < T_SZ; ++t) {
    // prefetch next step's gx under the MFMA phase
    float gxz_n = 0.f, gxr_n = 0.f, gxn_n = 0.f;
    if (t + 1 < T_SZ && tid < H_SZ) {
      const float* g1 = gxp + (size_t)(t + 1) * 768;
      gxz_n = g1[tid];
      gxr_n = g1[H_SZ + tid];
      gxn_n = g1[2 * H_SZ + tid];
    }

    f32x4 acc[6];
#pragma unroll
    for (int ni = 0; ni < 6; ++ni) acc[ni] = (f32x4){0.f, 0.f, 0.f, 0.f};
#pragma unroll
    for (int kk = 0; kk < 8; ++kk) {
      int c = kk * 4 + asub;
      f16x8 afrag = *(const f16x8*)((const char*)hlds + abase + ((c ^ aswz) << 4));
#pragma unroll
      for (int ni = 0; ni < 6; ++ni)
        acc[ni] = __builtin_amdgcn_mfma_f32_16x16x32_f16(afrag, Ufrag[ni][kk], acc[ni], 0, 0, 0);
    }
    // C row 0 = lanes 0..15, reg 0  [m89 layout: row=(lane>>4)*4+reg, col=lane&15]
    if (lane < 16) {
      const int nb = w * 96 + lane;
#pragma unroll
      for (int ni = 0; ni < 6; ++ni) ghbuf[nb + ni * 16] = acc[ni][0];
    }
    __syncthreads();

    if (tid < H_SZ) {
      float hz = ghbuf[tid] + buz;
      float hr = ghbuf[H_SZ + tid] + bur;
      float hn = ghbuf[2 * H_SZ + tid] + bun;
      float z = 1.f / (1.f + __expf(-(gxz + hz)));
      float r = 1.f / (1.f + __expf(-(gxr + hr)));
      float nv = 2.f / (1.f + __expf(-2.f * (gxn + r * hn))) - 1.f;  // tanh
      float hnew = (words_s[t] != 0) ? (z * h_old + (1.f - z) * nv) : h_old;
      h_old = hnew;
      seqb[((size_t)b * T_SZ + t) * H_SZ + tid] = f2bf(hnew);
      hlds[tid] = (_Float16)hnew;  // row 0, chunk swizzle is identity for row 0
    }
    __syncthreads();
    gxz = gxz_n;
    gxr = gxr_n;
    gxn = gxn_n;
  }
}

// ---------------- launcher ----------------
extern "C" void kernel_launch(void* const* d_in, const int* in_sizes, int n_in,
                              void* d_out, int out_size, void* d_ws, size_t ws_size,
                              hipStream_t stream) {
  const int*   words = (const int*)d_in[0];    // [32,256]
  const float* midis = (const float*)d_in[1];  // [32,256,128]
  const float* E     = (const float*)d_in[2];  // [10000,300]
  const float* Wm    = (const float*)d_in[3];  // [128,300]
  const float* bm    = (const float*)d_in[4];  // [300]
  const float* Wx    = (const float*)d_in[5];  // [300,768]
  const float* bx    = (const float*)d_in[6];  // [768]
  const float* U     = (const float*)d_in[7];  // [256,768]
  const float* bu    = (const float*)d_in[8];  // [768]
  const float* Wo    = (const float*)d_in[9];  // [256,10000]
  const float* bo    = (const float*)d_in[10]; // [10000]
  float* out = (float*)d_out;

  const int MT = B_SZ * T_SZ;  // 8192
  size_t off = 0;
  auto alloc = [&](size_t bytes) -> void* {
    void* p = (char*)d_ws + off;
    off += (bytes + 255) & ~(size_t)255;
    return p;
  };
  ushort_t* mid_b = (ushort_t*)alloc((size_t)MT * 128 * 2);
  ushort_t* WmT   = (ushort_t*)alloc((size_t)384 * 128 * 2);
  float*    xtmp  = (float*)   alloc((size_t)MT * 320 * 4);
  ushort_t* x_b   = (ushort_t*)alloc((size_t)MT * 320 * 2);
  ushort_t* WxT   = (ushort_t*)alloc((size_t)768 * 320 * 2);
  float*    gx    = (float*)   alloc((size_t)MT * 768 * 4);
  ushort_t* UT    = (ushort_t*)alloc((size_t)768 * 256 * 2);
  ushort_t* seq_b = (ushort_t*)alloc((size_t)MT * 256 * 2);
  ushort_t* WoT   = (ushort_t*)alloc((size_t)10112 * 256 * 2);
  (void)ws_size;

  // prep: casts + transposes
  k_cast_bf16<<<(MT * 128 + 255) / 256, 256, 0, stream>>>(midis, mid_b, MT * 128);
  k_transpose_cast<0><<<dim3(12, 4),  dim3(32, 8), 0, stream>>>(Wm, WmT, 128, 300, 128, 384);
  k_transpose_cast<0><<<dim3(24, 10), dim3(32, 8), 0, stream>>>(Wx, WxT, 300, 768, 320, 768);
  k_transpose_cast<0><<<dim3(316, 8), dim3(32, 8), 0, stream>>>(Wo, WoT, 256, 10000, 256, 10112);
  k_transpose_cast<1><<<dim3(24, 8),  dim3(32, 8), 0, stream>>>(U, UT, 256, 768, 256, 768);

  // xtmp = midis @ Wm + bm   (M=8192, K=128, Npad=384, Nreal=300, ldc=320)
  k_gemm_bt<<<dim3(64, 3), 256, 0, stream>>>(mid_b, WmT, bm, xtmp, MT, 128, 300, 320);
  // x_b = bf16(xtmp + E[words]) with k-pad zeros
  k_xfuse<<<MT, 320, 0, stream>>>(xtmp, E, words, x_b);
  // gx = x @ Wx + bx   (K=320, N=768)
  k_gemm_bt<<<dim3(64, 6), 256, 0, stream>>>(x_b, WxT, bx, gx, MT, 320, 768, 768);
  // GRU -> seq_b (bf16), round-2 proven 8-wave MFMA matvec
  k_gru<<<B_SZ, 512, 0, stream>>>(gx, UT, bu, words, seq_b);
  // logits = seq @ Wo + bo   (K=256, Npad=10112, Nreal=10000)
  k_gemm_bt<<<dim3(64, 79), 256, 0, stream>>>(seq_b, WoT, bo, out, MT, 256, 10000, 10000);
}